// Round 1
// baseline (312.854 us; speedup 1.0000x reference)
//
#include <hip/hip_runtime.h>

typedef __bf16 bf16_t;
typedef __bf16 bf16x8 __attribute__((ext_vector_type(8)));
typedef __bf16 bf16x4v __attribute__((ext_vector_type(4)));
typedef float f32x4 __attribute__((ext_vector_type(4)));

#define LN_EPS 1e-5f

__device__ __forceinline__ float gelu_f(float x) {
  return 0.5f * x * (1.0f + erff(x * 0.70710678118654752f));
}

__device__ __forceinline__ void async16(const bf16_t* g, bf16_t* l) {
  __builtin_amdgcn_global_load_lds(
      (const __attribute__((address_space(1))) void*)g,
      (__attribute__((address_space(3))) void*)l, 16, 0, 0);
}

// ---------------------------------------------------------------------------
// prep: X,S -> bf16 ; weights -> transposed (N-major) bf16
// ---------------------------------------------------------------------------
__global__ __launch_bounds__(256)
void prep_kernel(const float* __restrict__ X, const float* __restrict__ S,
                 const float* __restrict__ Wg, const float* __restrict__ Wk,
                 const float* __restrict__ Wm1, const float* __restrict__ Wgt1,
                 const float* __restrict__ Wm2, const float* __restrict__ Wqkv,
                 const float* __restrict__ Wo, const float* __restrict__ Wu1,
                 const float* __restrict__ Wu2,
                 bf16_t* __restrict__ Xb, bf16_t* __restrict__ Sb,
                 bf16_t* __restrict__ W1t, bf16_t* __restrict__ W2t,
                 bf16_t* __restrict__ Wqkvt, bf16_t* __restrict__ Wot,
                 bf16_t* __restrict__ Wu1t, bf16_t* __restrict__ Wu2t)
{
  const int bid = blockIdx.x;
  const int t = threadIdx.x;
  if (bid < 8192) {                       // X: 2,097,152 float4
    const int i = bid * 256 + t;
    const float4 v = ((const float4*)X)[i];
    bf16x4v o; o[0]=(bf16_t)v.x; o[1]=(bf16_t)v.y; o[2]=(bf16_t)v.z; o[3]=(bf16_t)v.w;
    ((bf16x4v*)Xb)[i] = o;
  } else if (bid < 9216) {                // S
    const int i = (bid - 8192) * 256 + t;
    const float4 v = ((const float4*)S)[i];
    bf16x4v o; o[0]=(bf16_t)v.x; o[1]=(bf16_t)v.y; o[2]=(bf16_t)v.z; o[3]=(bf16_t)v.w;
    ((bf16x4v*)Sb)[i] = o;
  } else if (bid < 10112) {               // W1t: 896 rows x 256
    const int n = bid - 9216;
    const int k = t;
    float v;
    if (n < 512)      v = Wm1[k * 512 + n];
    else if (n < 768) v = Wgt1[k * 256 + (n - 512)];
    else if (n < 832) v = Wg[k * 64 + (n - 768)];
    else if (n < 840) v = Wk[k * 8 + (n - 832)];
    else              v = 0.f;
    W1t[n * 256 + k] = (bf16_t)v;
  } else if (bid < 10368) {               // W2t: 256 rows x 512
    const int n = bid - 10112;
    for (int k = t; k < 512; k += 256) W2t[n * 512 + k] = (bf16_t)Wm2[k * 256 + n];
  } else if (bid < 11136) {               // Wqkvt: 768 x 256
    const int n = bid - 10368;
    Wqkvt[n * 256 + t] = (bf16_t)Wqkv[t * 768 + n];
  } else if (bid < 11392) {               // Wot: 256 x 256
    const int n = bid - 11136;
    Wot[n * 256 + t] = (bf16_t)Wo[t * 256 + n];
  } else if (bid < 11904) {               // Wu1t: 512 x 512
    const int n = bid - 11392;
    for (int k = t; k < 512; k += 256) Wu1t[n * 512 + k] = (bf16_t)Wu1[k * 512 + n];
  } else {                                // Wu2t: 256 x 512
    const int n = bid - 11904;
    for (int k = t; k < 512; k += 256) Wu2t[n * 512 + k] = (bf16_t)Wu2[k * 256 + n];
  }
}

// ---------------------------------------------------------------------------
// generic bf16 MFMA GEMM: C[M x N] = A[M x K] * Bt[N x K]^T, tile BMx128
// EPI: 1=gelu(+bm1/bgt1)->bf16 (G1, raw logits for col>=768)
//      2=(c+bias)*gate -> atomicAdd incoming (G2 scatter)
//      3=+bias->bf16   4=+bias->f32   5=gelu(+bias)->bf16   6=+bias+resid->f32
// ---------------------------------------------------------------------------
template<int MT, int EPI>
__global__ __launch_bounds__(256)
void gemm_kernel(const bf16_t* __restrict__ A, int lda,
                 const bf16_t* __restrict__ Bt, int K,
                 const float* __restrict__ bias, const float* __restrict__ bias2,
                 void* __restrict__ outp, int ldc,
                 const float* __restrict__ gate, const int* __restrict__ slotidx,
                 float* __restrict__ incoming, const float* __restrict__ resid)
{
  constexpr int BM = MT * 32;
  constexpr int IA = (BM * 4) / 256;
  const int m0 = blockIdx.x * BM;
  const int n0 = blockIdx.y * 128;
  const int t = threadIdx.x;
  const int w = t >> 6;
  const int lane = t & 63;
  const int wr = w >> 1, wc = w & 1;
  const int quad = lane >> 4, l15 = lane & 15;

  __shared__ bf16_t lA[BM * 32];
  __shared__ bf16_t lB[128 * 32];

  f32x4 acc[MT][4];
#pragma unroll
  for (int mt = 0; mt < MT; ++mt)
#pragma unroll
    for (int nt = 0; nt < 4; ++nt)
      acc[mt][nt] = (f32x4){0.f, 0.f, 0.f, 0.f};

  for (int k0 = 0; k0 < K; k0 += 32) {
#pragma unroll
    for (int i = 0; i < IA; ++i) {
      const int c = i * 256 + t;
      async16(A + (size_t)(m0 + (c >> 2)) * lda + k0 + (c & 3) * 8,
              lA + (size_t)(i * 256 + (t & 192)) * 8);
    }
#pragma unroll
    for (int i = 0; i < 2; ++i) {
      const int c = i * 256 + t;
      async16(Bt + (size_t)(n0 + (c >> 2)) * K + k0 + (c & 3) * 8,
              lB + (size_t)(i * 256 + (t & 192)) * 8);
    }
    __syncthreads();
    bf16x8 af[MT], bfr[4];
    const int ko = quad * 8;
#pragma unroll
    for (int mt = 0; mt < MT; ++mt)
      af[mt] = *(const bf16x8*)&lA[(wr * MT * 16 + mt * 16 + l15) * 32 + ko];
#pragma unroll
    for (int nt = 0; nt < 4; ++nt)
      bfr[nt] = *(const bf16x8*)&lB[(wc * 64 + nt * 16 + l15) * 32 + ko];
#pragma unroll
    for (int mt = 0; mt < MT; ++mt)
#pragma unroll
      for (int nt = 0; nt < 4; ++nt)
        acc[mt][nt] = __builtin_amdgcn_mfma_f32_16x16x32_bf16(af[mt], bfr[nt], acc[mt][nt], 0, 0, 0);
    __syncthreads();
  }

#pragma unroll
  for (int mt = 0; mt < MT; ++mt) {
#pragma unroll
    for (int nt = 0; nt < 4; ++nt) {
#pragma unroll
      for (int r = 0; r < 4; ++r) {
        const int row = m0 + wr * MT * 16 + mt * 16 + quad * 4 + r;
        const int col = n0 + wc * 64 + nt * 16 + l15;
        float v = acc[mt][nt][r];
        if constexpr (EPI == 1) {
          if (col < 768) {
            const float bb = (col < 512) ? bias[col] : bias2[col - 512];
            v = gelu_f(v + bb);
          }
          ((bf16_t*)outp)[(size_t)row * ldc + col] = (bf16_t)v;
        } else if constexpr (EPI == 2) {
          v = (v + bias[col]) * gate[row];
          atomicAdd(&incoming[(size_t)(((row >> 12) << 9) + slotidx[row]) * 256 + col], v);
        } else if constexpr (EPI == 3) {
          ((bf16_t*)outp)[(size_t)row * ldc + col] = (bf16_t)(v + bias[col]);
        } else if constexpr (EPI == 4) {
          ((float*)outp)[(size_t)row * ldc + col] = v + bias[col];
        } else if constexpr (EPI == 5) {
          ((bf16_t*)outp)[(size_t)row * ldc + col] = (bf16_t)gelu_f(v + bias[col]);
        } else {
          ((float*)outp)[(size_t)row * ldc + col] = v + bias[col] + resid[(size_t)row * ldc + col];
        }
      }
    }
  }
}

// ---------------------------------------------------------------------------
// route: gate = sigmoid(g1.Wgt2 + bgt2); idx = argmax(g)*8 + argmax(k)
// wave per token; first-index tie-break to match jnp.argmax
// ---------------------------------------------------------------------------
__global__ __launch_bounds__(256)
void route_kernel(const bf16_t* __restrict__ h1g1, const float* __restrict__ Wgt2,
                  const float* __restrict__ bgt2, int* __restrict__ idxb,
                  float* __restrict__ gateb)
{
  const int w = threadIdx.x >> 6, lane = threadIdx.x & 63;
  const int m = blockIdx.x * 4 + w;
  const bf16_t* rowp = h1g1 + (size_t)m * 896;

  bf16x4v g4 = *(const bf16x4v*)&rowp[512 + lane * 4];
  float s = 0.f;
#pragma unroll
  for (int j = 0; j < 4; ++j) s += (float)g4[j] * Wgt2[lane * 4 + j];
#pragma unroll
  for (int off = 32; off; off >>= 1) s += __shfl_xor(s, off, 64);
  const float gate = 1.0f / (1.0f + __expf(-(s + bgt2[0])));

  float vg = (float)rowp[768 + lane];
  int ig = lane;
#pragma unroll
  for (int off = 32; off; off >>= 1) {
    const float ov = __shfl_xor(vg, off, 64);
    const int oi = __shfl_xor(ig, off, 64);
    if (ov > vg || (ov == vg && oi < ig)) { vg = ov; ig = oi; }
  }
  float vk = (lane < 8) ? (float)rowp[832 + lane] : -1e30f;
  int ik = lane;
#pragma unroll
  for (int off = 32; off; off >>= 1) {
    const float ov = __shfl_xor(vk, off, 64);
    const int oi = __shfl_xor(ik, off, 64);
    if (ov > vk || (ov == vk && oi < ik)) { vk = ov; ik = oi; }
  }
  if (lane == 0) { idxb[m] = ig * 8 + ik; gateb[m] = gate; }
}

// ---------------------------------------------------------------------------
// fused slot attention: block = (b, h, 32-query chunk); scores+softmax in LDS
// ---------------------------------------------------------------------------
__global__ __launch_bounds__(256)
void attn_kernel(const bf16_t* __restrict__ qkv, bf16_t* __restrict__ obuf)
{
  const int bid = blockIdx.x;
  const int qc = bid & 15;
  const int h = (bid >> 4) & 7;
  const int b = bid >> 7;
  const int t = threadIdx.x;
  const int w = t >> 6, lane = t & 63;
  const int quad = lane >> 4, l15 = lane & 15;

  __shared__ bf16_t sP[32 * 520];    // scores/P, stride 520 (16B-aligned rows)
  __shared__ bf16_t sVt[32 * 264];   // V^T half (32 dh x 256 keys), padded
  __shared__ float sL[32];

  // pass A: scores
  bf16x8 qf[2];
#pragma unroll
  for (int mt = 0; mt < 2; ++mt) {
    const int row = b * 512 + qc * 32 + mt * 16 + l15;
    qf[mt] = *(const bf16x8*)&qkv[(size_t)row * 768 + h * 32 + quad * 8];
  }
  const float scale = 0.17677669529663687f;  // 1/sqrt(32)
  for (int kt = w; kt < 32; kt += 4) {
    const int key = b * 512 + kt * 16 + l15;
    const bf16x8 kf = *(const bf16x8*)&qkv[(size_t)key * 768 + 256 + h * 32 + quad * 8];
#pragma unroll
    for (int mt = 0; mt < 2; ++mt) {
      f32x4 c = (f32x4){0.f, 0.f, 0.f, 0.f};
      c = __builtin_amdgcn_mfma_f32_16x16x32_bf16(qf[mt], kf, c, 0, 0, 0);
#pragma unroll
      for (int r = 0; r < 4; ++r)
        sP[(mt * 16 + quad * 4 + r) * 520 + kt * 16 + l15] = (bf16_t)(c[r] * scale);
    }
  }
  __syncthreads();

  // pass B: softmax (store P = exp(s - max), keep row sums)
#pragma unroll
  for (int ri = 0; ri < 8; ++ri) {
    const int row = w * 8 + ri;
    const bf16x8 sv = *(const bf16x8*)&sP[row * 520 + lane * 8];
    float sval[8];
    float mx = -1e30f;
#pragma unroll
    for (int j = 0; j < 8; ++j) { sval[j] = (float)sv[j]; mx = fmaxf(mx, sval[j]); }
#pragma unroll
    for (int off = 32; off; off >>= 1) mx = fmaxf(mx, __shfl_xor(mx, off, 64));
    float sum = 0.f;
    bf16x8 pv;
#pragma unroll
    for (int j = 0; j < 8; ++j) { const float e = __expf(sval[j] - mx); sum += e; pv[j] = (bf16_t)e; }
#pragma unroll
    for (int off = 32; off; off >>= 1) sum += __shfl_xor(sum, off, 64);
    *(bf16x8*)&sP[row * 520 + lane * 8] = pv;
    if (lane == 0) sL[row] = sum;
  }
  __syncthreads();

  // pass C: o = P @ V  (wave -> one 16x16 output tile)
  const int omt = w >> 1, ont = w & 1;
  f32x4 oacc = (f32x4){0.f, 0.f, 0.f, 0.f};
  for (int half = 0; half < 2; ++half) {
    if (half) __syncthreads();
#pragma unroll
    for (int i = 0; i < 32; ++i) {
      const int el = i * 256 + t;
      const int dh = el & 31, key = el >> 5;
      sVt[dh * 264 + key] = qkv[(size_t)(b * 512 + half * 256 + key) * 768 + 512 + h * 32 + dh];
    }
    __syncthreads();
#pragma unroll
    for (int kt = 0; kt < 8; ++kt) {
      const bf16x8 af = *(const bf16x8*)&sP[(omt * 16 + l15) * 520 + half * 256 + kt * 32 + quad * 8];
      const bf16x8 vf = *(const bf16x8*)&sVt[(ont * 16 + l15) * 264 + kt * 32 + quad * 8];
      oacc = __builtin_amdgcn_mfma_f32_16x16x32_bf16(af, vf, oacc, 0, 0, 0);
    }
  }
#pragma unroll
  for (int r = 0; r < 4; ++r) {
    const int row = omt * 16 + quad * 4 + r;
    const float val = oacc[r] / sL[row];
    obuf[(size_t)(b * 512 + qc * 32 + row) * 256 + h * 32 + ont * 16 + l15] = (bf16_t)val;
  }
}

// ---------------------------------------------------------------------------
// LN1: S1 = LN(S + o2); pack A4 = [bf16(S1) | bf16(incoming)]; keep S1 fp32
// ---------------------------------------------------------------------------
__global__ __launch_bounds__(256)
void ln1_kernel(const float* __restrict__ S, const float* __restrict__ o2,
                const float* __restrict__ incom, const float* __restrict__ g,
                const float* __restrict__ bb, float* __restrict__ S1f,
                bf16_t* __restrict__ A4)
{
  const int w = threadIdx.x >> 6, lane = threadIdx.x & 63;
  const int row = blockIdx.x * 4 + w;
  const size_t base = (size_t)row * 256 + lane * 4;
  const float4 xs = *(const float4*)&S[base];
  const float4 xo = *(const float4*)&o2[base];
  float x[4] = {xs.x + xo.x, xs.y + xo.y, xs.z + xo.z, xs.w + xo.w};
  float sum = x[0] + x[1] + x[2] + x[3];
  float sq = x[0]*x[0] + x[1]*x[1] + x[2]*x[2] + x[3]*x[3];
#pragma unroll
  for (int off = 32; off; off >>= 1) { sum += __shfl_xor(sum, off, 64); sq += __shfl_xor(sq, off, 64); }
  const float mean = sum * 0.00390625f;
  const float var = sq * 0.00390625f - mean * mean;
  const float rstd = rsqrtf(var + LN_EPS);
  const float4 gg = *(const float4*)&g[lane * 4];
  const float4 bv = *(const float4*)&bb[lane * 4];
  float y[4];
  y[0] = (x[0]-mean)*rstd*gg.x + bv.x;
  y[1] = (x[1]-mean)*rstd*gg.y + bv.y;
  y[2] = (x[2]-mean)*rstd*gg.z + bv.z;
  y[3] = (x[3]-mean)*rstd*gg.w + bv.w;
  *(float4*)&S1f[base] = make_float4(y[0], y[1], y[2], y[3]);
  bf16x4v yb; yb[0]=(bf16_t)y[0]; yb[1]=(bf16_t)y[1]; yb[2]=(bf16_t)y[2]; yb[3]=(bf16_t)y[3];
  *(bf16x4v*)&A4[(size_t)row * 512 + lane * 4] = yb;
  const float4 ic = *(const float4*)&incom[base];
  bf16x4v ib; ib[0]=(bf16_t)ic.x; ib[1]=(bf16_t)ic.y; ib[2]=(bf16_t)ic.z; ib[3]=(bf16_t)ic.w;
  *(bf16x4v*)&A4[(size_t)row * 512 + 256 + lane * 4] = ib;
}

__global__ __launch_bounds__(256)
void ln2_kernel(const float* __restrict__ S2, const float* __restrict__ g,
                const float* __restrict__ bb, float* __restrict__ out)
{
  const int w = threadIdx.x >> 6, lane = threadIdx.x & 63;
  const int row = blockIdx.x * 4 + w;
  const size_t base = (size_t)row * 256 + lane * 4;
  const float4 xv = *(const float4*)&S2[base];
  float x[4] = {xv.x, xv.y, xv.z, xv.w};
  float sum = x[0] + x[1] + x[2] + x[3];
  float sq = x[0]*x[0] + x[1]*x[1] + x[2]*x[2] + x[3]*x[3];
#pragma unroll
  for (int off = 32; off; off >>= 1) { sum += __shfl_xor(sum, off, 64); sq += __shfl_xor(sq, off, 64); }
  const float mean = sum * 0.00390625f;
  const float var = sq * 0.00390625f - mean * mean;
  const float rstd = rsqrtf(var + LN_EPS);
  const float4 gg = *(const float4*)&g[lane * 4];
  const float4 bv = *(const float4*)&bb[lane * 4];
  float4 o;
  o.x = (x[0]-mean)*rstd*gg.x + bv.x;
  o.y = (x[1]-mean)*rstd*gg.y + bv.y;
  o.z = (x[2]-mean)*rstd*gg.z + bv.z;
  o.w = (x[3]-mean)*rstd*gg.w + bv.w;
  *(float4*)&out[base] = o;
}

// ---------------------------------------------------------------------------
extern "C" void kernel_launch(void* const* d_in, const int* in_sizes, int n_in,
                              void* d_out, int out_size, void* d_ws, size_t ws_size,
                              hipStream_t stream)
{
  (void)in_sizes; (void)n_in; (void)out_size; (void)ws_size;
  const float* X    = (const float*)d_in[0];
  const float* S    = (const float*)d_in[1];
  const float* Wg   = (const float*)d_in[2];
  const float* Wk   = (const float*)d_in[3];
  const float* Wm1  = (const float*)d_in[4];
  const float* bm1  = (const float*)d_in[5];
  const float* Wm2  = (const float*)d_in[6];
  const float* bm2  = (const float*)d_in[7];
  const float* Wgt1 = (const float*)d_in[8];
  const float* bgt1 = (const float*)d_in[9];
  const float* Wgt2 = (const float*)d_in[10];
  const float* bgt2 = (const float*)d_in[11];
  const float* Wqkv = (const float*)d_in[12];
  const float* bqkv = (const float*)d_in[13];
  const float* Wo   = (const float*)d_in[14];
  const float* bo   = (const float*)d_in[15];
  const float* alng = (const float*)d_in[16];
  const float* alnb = (const float*)d_in[17];
  const float* Wu1  = (const float*)d_in[18];
  const float* bu1  = (const float*)d_in[19];
  const float* Wu2  = (const float*)d_in[20];
  const float* bu2  = (const float*)d_in[21];
  const float* lng  = (const float*)d_in[22];
  const float* lnb  = (const float*)d_in[23];

  char* p = (char*)d_ws;
  auto carve = [&](size_t bytes) { char* r = p; p += bytes; return r; };
  bf16_t* Xb    = (bf16_t*)carve(16777216);   // 32768 x 256
  bf16_t* Sb    = (bf16_t*)carve(2097152);    // 4096 x 256
  bf16_t* W1t   = (bf16_t*)carve(458752);     // 896 x 256
  bf16_t* W2t   = (bf16_t*)carve(262144);     // 256 x 512
  bf16_t* Wqkvt = (bf16_t*)carve(393216);     // 768 x 256
  bf16_t* Wot   = (bf16_t*)carve(131072);     // 256 x 256
  bf16_t* Wu1t  = (bf16_t*)carve(524288);     // 512 x 512
  bf16_t* Wu2t  = (bf16_t*)carve(262144);     // 256 x 512
  bf16_t* h1g1  = (bf16_t*)carve(58720256);   // 32768 x 896
  int*    idxb  = (int*)carve(131072);
  float*  gateb = (float*)carve(131072);
  float*  incom = (float*)carve(4194304);     // 4096 x 256 f32
  bf16_t* qkvb  = (bf16_t*)carve(6291456);    // 4096 x 768
  bf16_t* obuf  = (bf16_t*)carve(2097152);    // 4096 x 256
  float*  o2    = (float*)carve(4194304);
  float*  S1f   = (float*)carve(4194304);
  bf16_t* A4    = (bf16_t*)carve(4194304);    // 4096 x 512
  bf16_t* U     = (bf16_t*)carve(4194304);    // 4096 x 512
  float*  S2    = (float*)carve(4194304);

  prep_kernel<<<12160, 256, 0, stream>>>(X, S, Wg, Wk, Wm1, Wgt1, Wm2, Wqkv, Wo, Wu1, Wu2,
                                         Xb, Sb, W1t, W2t, Wqkvt, Wot, Wu1t, Wu2t);
  hipMemsetAsync(incom, 0, 4194304, stream);
  // G1: X @ [Wm1|Wgt1|Wg|Wk]
  gemm_kernel<4,1><<<dim3(256,7), 256, 0, stream>>>(Xb, 256, W1t, 256, bm1, bgt1, h1g1, 896,
                                                    nullptr, nullptr, nullptr, nullptr);
  route_kernel<<<8192, 256, 0, stream>>>(h1g1, Wgt2, bgt2, idxb, gateb);
  // G2: h1 @ Wm2 -> *gate -> scatter-add incoming
  gemm_kernel<4,2><<<dim3(256,2), 256, 0, stream>>>(h1g1, 896, W2t, 512, bm2, nullptr, nullptr, 0,
                                                    gateb, idxb, incom, nullptr);
  // qkv
  gemm_kernel<2,3><<<dim3(64,6), 256, 0, stream>>>(Sb, 256, Wqkvt, 256, bqkv, nullptr, qkvb, 768,
                                                   nullptr, nullptr, nullptr, nullptr);
  attn_kernel<<<1024, 256, 0, stream>>>(qkvb, obuf);
  // o @ Wo
  gemm_kernel<2,4><<<dim3(64,2), 256, 0, stream>>>(obuf, 256, Wot, 256, bo, nullptr, o2, 256,
                                                   nullptr, nullptr, nullptr, nullptr);
  ln1_kernel<<<1024, 256, 0, stream>>>(S, o2, incom, alng, alnb, S1f, A4);
  // update MLP
  gemm_kernel<2,5><<<dim3(64,4), 256, 0, stream>>>(A4, 512, Wu1t, 512, bu1, nullptr, U, 512,
                                                   nullptr, nullptr, nullptr, nullptr);
  gemm_kernel<2,6><<<dim3(64,2), 256, 0, stream>>>(U, 512, Wu2t, 512, bu2, nullptr, S2, 256,
                                                   nullptr, nullptr, nullptr, S1f);
  ln2_kernel<<<1024, 256, 0, stream>>>(S2, lng, lnb, (float*)d_out);
}